// Round 14
// baseline (233.848 us; speedup 1.0000x reference)
//
#include <hip/hip_runtime.h>
#include <hip/hip_bf16.h>
#include <stdint.h>

// SimpleSSM: y = (scan_t h=tanh(A*h + x@W_B^T + b_B)) @ W_C^T + b_C
// B=8, L=2048, D=1024.  All fp32 in/out.
// R14 = R8 components (unchanged GEMM/rec bodies) re-organized as a
// LAUNCH-LEVEL pipeline over 4 t-chunks: launch i runs {rec(chunk i-1),
// GEMM1(chunk i), GEMM2(chunk i-2)} as block roles of one kernel. All
// dependencies are cross-launch (stream order) -> no intra-launch sync.
// Rec (0.7% occupancy, ~67us) now overlaps the GEMMs.
// Split-fp16 GEMM1 mandatory (R2/R3: non-split chaos-amplifies to 0.25).

using half8 = __attribute__((ext_vector_type(8))) _Float16;  // 8 fp16
using f32x4 = __attribute__((ext_vector_type(4))) float;

#define DEV __device__ __forceinline__

#if __has_builtin(__builtin_amdgcn_exp2f)
DEV float pexp(float x) { return __builtin_amdgcn_exp2f(x); }
constexpr float BX_SCALE = 2.8853900817779268f;   // 2*log2(e): exp2 domain
#else
DEV float pexp(float x) { return __expf(x); }
constexpr float BX_SCALE = 2.0f;                   // e^x domain
#endif

DEV ushort f2h(float x) {
  union { _Float16 f; ushort u; } c;
  c.f = (_Float16)x;          // v_cvt_f16_f32, RNE
  return c.u;
}
DEV float h2f(ushort u) {
  union { ushort u; _Float16 f; } c;
  c.u = u;
  return (float)c.f;
}

DEV void gload_lds16(const void* g, void* l) {
  __builtin_amdgcn_global_load_lds((const __attribute__((address_space(1))) void*)g,
                                   (__attribute__((address_space(3))) void*)l,
                                   16, 0, 0);
}

// ---------------- single conversion kernel ----------------
__global__ void k_convert_all(const float* __restrict__ X, const float* __restrict__ WB,
                              const float* __restrict__ WC,
                              ushort* __restrict__ xh, ushort* __restrict__ xl,
                              ushort* __restrict__ wbh, ushort* __restrict__ wbl,
                              ushort* __restrict__ wch, int n4x, int n4w) {
  const int stride = gridDim.x * blockDim.x;
  const int total = n4x + 2 * n4w;
  for (int i = blockIdx.x * blockDim.x + threadIdx.x; i < total; i += stride) {
    if (i < n4x) {
      float4 v = reinterpret_cast<const float4*>(X)[i];
      ushort4 hv, lv;
      hv.x = f2h(v.x); lv.x = f2h(v.x - h2f(hv.x));
      hv.y = f2h(v.y); lv.y = f2h(v.y - h2f(hv.y));
      hv.z = f2h(v.z); lv.z = f2h(v.z - h2f(hv.z));
      hv.w = f2h(v.w); lv.w = f2h(v.w - h2f(hv.w));
      reinterpret_cast<ushort4*>(xh)[i] = hv;
      reinterpret_cast<ushort4*>(xl)[i] = lv;
    } else if (i < n4x + n4w) {
      const int j = i - n4x;
      float4 v = reinterpret_cast<const float4*>(WB)[j];
      ushort4 hv, lv;
      hv.x = f2h(v.x); lv.x = f2h(v.x - h2f(hv.x));
      hv.y = f2h(v.y); lv.y = f2h(v.y - h2f(hv.y));
      hv.z = f2h(v.z); lv.z = f2h(v.z - h2f(hv.z));
      hv.w = f2h(v.w); lv.w = f2h(v.w - h2f(hv.w));
      reinterpret_cast<ushort4*>(wbh)[j] = hv;
      reinterpret_cast<ushort4*>(wbl)[j] = lv;
    } else {
      const int j = i - n4x - n4w;
      float4 v = reinterpret_cast<const float4*>(WC)[j];
      ushort4 hv;
      hv.x = f2h(v.x); hv.y = f2h(v.y);
      hv.z = f2h(v.z); hv.w = f2h(v.w);
      reinterpret_cast<ushort4*>(wch)[j] = hv;
    }
  }
}

// ---------------- GEMM role (R8 body, chunked bm) --------------------------
// One t-chunk = 512 steps = 4 bm-tiles per batch.  g in [0,256):
// xcd = g&7, s = g>>3, tile-in-chunk tc = (s&~7)|xcd (xcd owns tc ≡ xcd mod 8
// -> same per-XCD A-panel locality as R8), bn = s&7,
// bm = (tc>>2)*16 + chunk*4 + (tc&3).
template <int SPLIT, int SCALE>
DEV void gemm_role(const ushort* __restrict__ Ah, const ushort* __restrict__ Al,
                   const ushort* __restrict__ Bh, const ushort* __restrict__ Bl,
                   const float* __restrict__ bias, const float* __restrict__ Avec,
                   float* __restrict__ C, int chunk, int g, ushort* lds) {
  constexpr int K = 1024, N = 1024;
  ushort* sAh = lds;
  ushort* sAl = lds + (SPLIT ? 8192 : 0);
  ushort* sBh = lds + (SPLIT ? 16384 : 8192);
  ushort* sBl = lds + (SPLIT ? 24576 : 8192);

  const int t = threadIdx.x;
  const int lane = t & 63;
  const int w = t >> 6;
  const int wm = w >> 1, wn = w & 1;

  const int xcd = g & 7, s = g >> 3;
  const int tc = (s & ~7) | xcd;
  const int bn = s & 7;
  const int bm = ((tc >> 2) << 4) + chunk * 4 + (tc & 3);

  const int lr = lane & 15;
  const int lk = (lane >> 4) << 3;

  const ushort* gA_h = Ah + (size_t)(bm * 128) * K;
  const ushort* gA_l = SPLIT ? (Al + (size_t)(bm * 128) * K) : gA_h;
  const ushort* gB_h = Bh + (size_t)(bn * 128) * K;
  const ushort* gB_l = SPLIT ? (Bl + (size_t)(bn * 128) * K) : gB_h;

  f32x4 acc[4][4];
#pragma unroll
  for (int i = 0; i < 4; ++i)
#pragma unroll
    for (int j = 0; j < 4; ++j)
#pragma unroll
      for (int r = 0; r < 4; ++r) acc[i][j][r] = 0.f;

  auto stage = [&](int kt) {
    const int k0 = kt * 64;
#pragma unroll
    for (int i = 0; i < 4; ++i) {
      const int lin16 = i * 256 + t;
      const int lb = lin16 << 4;
      const int row = lb >> 7;
      const int srcb = (lb & 127) ^ ((row & 7) << 4);
      const size_t goff = (size_t)row * K + (size_t)(k0 + (srcb >> 1));
      const int lidx = i * 2048 + w * 512;
      gload_lds16(gA_h + goff, sAh + lidx);
      if (SPLIT) gload_lds16(gA_l + goff, sAl + lidx);
      gload_lds16(gB_h + goff, sBh + lidx);
      if (SPLIT) gload_lds16(gB_l + goff, sBl + lidx);
    }
  };

  auto ldfrag = [&](const ushort* sp, int row, int kc) -> half8 {
    const int byte = (row << 7) + (((kc << 1) ^ ((row & 7) << 4)));
    return *reinterpret_cast<const half8*>(reinterpret_cast<const char*>(sp) + byte);
  };

  const int NT = K / 64;
  stage(0);
  for (int kt = 0; kt < NT; ++kt) {
    __syncthreads();
#pragma unroll
    for (int kk = 0; kk < 2; ++kk) {
      half8 ah[4], bh[4], al[4], bl[4];
      const int kc = kk * 32 + lk;
#pragma unroll
      for (int i = 0; i < 4; ++i) {
        const int row = wm * 64 + i * 16 + lr;
        ah[i] = ldfrag(sAh, row, kc);
        if (SPLIT) al[i] = ldfrag(sAl, row, kc);
      }
#pragma unroll
      for (int j = 0; j < 4; ++j) {
        const int row = wn * 64 + j * 16 + lr;
        bh[j] = ldfrag(sBh, row, kc);
        if (SPLIT) bl[j] = ldfrag(sBl, row, kc);
      }
#pragma unroll
      for (int i = 0; i < 4; ++i)
#pragma unroll
        for (int j = 0; j < 4; ++j) {
          acc[i][j] = __builtin_amdgcn_mfma_f32_16x16x32_f16(ah[i], bh[j], acc[i][j], 0, 0, 0);
          if (SPLIT) {
            acc[i][j] = __builtin_amdgcn_mfma_f32_16x16x32_f16(al[i], bh[j], acc[i][j], 0, 0, 0);
            acc[i][j] = __builtin_amdgcn_mfma_f32_16x16x32_f16(ah[i], bl[j], acc[i][j], 0, 0, 0);
          }
        }
    }
    __syncthreads();
    if (kt + 1 < NT) stage(kt + 1);
  }

  float* Cb = C + (size_t)(bm * 128) * N + bn * 128;
#pragma unroll
  for (int i = 0; i < 4; ++i)
#pragma unroll
    for (int j = 0; j < 4; ++j) {
      const int col = wn * 64 + j * 16 + lr;
      float bv = bias[bn * 128 + col];
      if (SCALE) bv += Avec[bn * 128 + col];
#pragma unroll
      for (int r = 0; r < 4; ++r) {
        const int rowt = wm * 64 + i * 16 + ((lane >> 4) << 2) + r;
        float o = acc[i][j][r] + bv;
        if (SCALE) o *= BX_SCALE;
        Cb[(size_t)rowt * N + col] = o;
      }
    }
}

// ---------------- recurrence role (R8 body, 512-step chunk) ----------------
// State r (h = 1-2r) carried across launches in hs[8192]; cr==0 initializes
// r=0.5 (replay-deterministic).  Chain: fma -> exp2 -> +1 -> rcp; ping-pong
// P=32 prefetch.  Identical per-channel op order to R8 -> bit-identical.
DEV void rec_role(const float* __restrict__ Bx2, const float* __restrict__ Avec,
                  ushort* __restrict__ Hout, float* __restrict__ hs,
                  int cr, int rbid) {
  const int tid = rbid * 256 + (int)threadIdx.x;   // 0..8191
  const int b = tid >> 10;
  const int d = tid & 1023;
  const float na2 = -2.f * BX_SCALE * Avec[d];
  const float* bx = Bx2 + (size_t)(b * 2048 + cr * 512) * 1024 + d;
  ushort* ho = Hout + (size_t)(b * 2048 + cr * 512) * 1024 + d;

  constexpr int P = 32;
  constexpr int NC = 512 / P;   // 16 chunks, even
  float cA[P], cB[P];
#pragma unroll
  for (int i = 0; i < P; ++i) cA[i] = bx[(size_t)i * 1024];
#pragma unroll
  for (int i = 0; i < P; ++i) cB[i] = bx[(size_t)(P + i) * 1024];

  float r = (cr == 0) ? 0.5f : hs[tid];
  for (int c = 0; c < NC; c += 2) {
#pragma unroll
    for (int i = 0; i < P; ++i) {
      const float u2 = fmaf(na2, r, cA[i]);
      r = __builtin_amdgcn_rcpf(pexp(u2) + 1.f);
      ho[(size_t)(c * P + i) * 1024] = f2h(fmaf(-2.f, r, 1.f));
    }
    if (c + 2 < NC) {
#pragma unroll
      for (int i = 0; i < P; ++i) cA[i] = bx[(size_t)((c + 2) * P + i) * 1024];
    }
#pragma unroll
    for (int i = 0; i < P; ++i) {
      const float u2 = fmaf(na2, r, cB[i]);
      r = __builtin_amdgcn_rcpf(pexp(u2) + 1.f);
      ho[(size_t)((c + 1) * P + i) * 1024] = f2h(fmaf(-2.f, r, 1.f));
    }
    if (c + 3 < NC) {
#pragma unroll
      for (int i = 0; i < P; ++i) cB[i] = bx[(size_t)((c + 3) * P + i) * 1024];
    }
  }
  hs[tid] = r;
}

// ---------------- combined pipeline kernel ----------------
// Block roles: [0,nr) rec(cr) | [nr, nr+n1) GEMM1(c1) | rest GEMM2(c2).
// Rec blocks first so they dispatch earliest (longest pole per launch).
__global__ __launch_bounds__(256, 2)
void k_combo(const ushort* __restrict__ xh, const ushort* __restrict__ xl,
             const ushort* __restrict__ wbh, const ushort* __restrict__ wbl,
             const ushort* __restrict__ wch,
             const float* __restrict__ bB, const float* __restrict__ bC,
             const float* __restrict__ Avec,
             float* __restrict__ Bx, ushort* __restrict__ h,
             float* __restrict__ hs, float* __restrict__ y,
             int cr, int c1, int nr, int c2) {
  extern __shared__ ushort lds[];
  int bid = blockIdx.x;
  if (bid < nr) { rec_role(Bx, Avec, h, hs, cr, bid); return; }
  bid -= nr;
  if (c1 >= 0) {
    if (bid < 256) {
      gemm_role<1, 1>(xh, xl, wbh, wbl, bB, Avec, Bx, c1, bid, lds);
      return;
    }
    bid -= 256;
  }
  gemm_role<0, 0>(h, (const ushort*)nullptr, wch, (const ushort*)nullptr,
                  bC, (const float*)nullptr, y, c2, bid, lds);
}

// ---------------- launch ----------------
extern "C" void kernel_launch(void* const* d_in, const int* in_sizes, int n_in,
                              void* d_out, int out_size, void* d_ws, size_t ws_size,
                              hipStream_t stream) {
  const float* x   = (const float*)d_in[0];
  const float* A   = (const float*)d_in[1];
  const float* W_B = (const float*)d_in[2];
  const float* b_B = (const float*)d_in[3];
  const float* W_C = (const float*)d_in[4];
  const float* b_C = (const float*)d_in[5];
  float* y = (float*)d_out;

  const int Bsz = 8, L = 2048, D = 1024;
  const int M = Bsz * L;                       // 16384

  char* ws = (char*)d_ws;
  ushort* x_hi = (ushort*)(ws);                 // 32MB fp16
  ushort* x_lo = (ushort*)(ws + 33554432);      // 32MB fp16
  ushort* wbh  = (ushort*)(ws + 67108864);      // 2MB
  ushort* wbl  = (ushort*)(ws + 69206016);      // 2MB
  ushort* wch  = (ushort*)(ws + 71303168);      // 2MB
  float*  Bx   = (float*)(ws + 73400320);       // 64MB fp32 scaled
  float*  hs   = (float*)(ws + 140509184);      // 32KB scan state
  ushort* h    = x_hi;   // alias: rec writes h rows of chunk c while GEMM1
                         // reads x rows of chunk c+1 -> disjoint rows.

  k_convert_all<<<2048, 256, 0, stream>>>(x, W_B, W_C, x_hi, x_lo, wbh, wbl, wch,
                                          M * D / 4, D * D / 4);

  auto combo = [&](int cr, int c1, int c2) {
    const int nr = (cr >= 0) ? 32 : 0;
    const int n1 = (c1 >= 0) ? 256 : 0;
    const int n2 = (c2 >= 0) ? 256 : 0;
    const size_t sh = (c1 >= 0) ? 65536 : 32768;
    k_combo<<<nr + n1 + n2, 256, sh, stream>>>(
        x_hi, x_lo, wbh, wbl, wch, b_B, b_C, A, Bx, h, hs, y, cr, c1, nr, c2);
  };

  // 4-chunk pipeline: launch i = {rec(i-1), GEMM1(i), GEMM2(i-2)}.
  combo(-1, 0, -1);
  combo( 0, 1, -1);
  combo( 1, 2,  0);
  combo( 2, 3,  1);
  combo( 3, -1, 2);
  combo(-1, -1, 3);
}